// Round 17
// baseline (209.173 us; speedup 1.0000x reference)
//
#include <hip/hip_runtime.h>
#include <hip/hip_bf16.h>
#include <math.h>

#define Bb   8
#define Qq   300
#define Cc   256
#define NHh  8
#define DHh  32
#define Ss   21760
#define DFFf 1024
#define LN_EPS 1e-5f

typedef __hip_bfloat16 bf16;
typedef unsigned short u16;
typedef unsigned int u32;
typedef __bf16 bf16x8_t __attribute__((ext_vector_type(8)));
typedef __bf16 bf16x4_t __attribute__((ext_vector_type(4)));
typedef float f32x4_t __attribute__((ext_vector_type(4)));

__device__ inline u16 f2bf(float f) {
  union { float f; u32 u; } v; v.f = f;
  u32 u = v.u + 0x7fffu + ((v.u >> 16) & 1u);
  return (u16)(u >> 16);
}
__device__ inline float bfbits_lo(u32 w) {
  union { u32 u; float f; } v; v.u = w << 16;
  return v.f;
}
__device__ inline float bfbits_hi(u32 w) {
  union { u32 u; float f; } v; v.u = w & 0xffff0000u;
  return v.f;
}

// LDS A-tile: packed [R][256] bf16 with 16B-chunk XOR swizzle (T2):
// physical chunk = logical chunk ^ (row & 7).
__device__ inline __bf16* lds_bf16(__bf16* base, int row, int chunk, int sub) {
  return base + (row << 8) + (((chunk ^ (row & 7)) << 3) + sub);
}

// Packed-weight fragment bases (in 512-elem frag units).
#define FR_WQ    0
#define FR_WK    128
#define FR_WV    256
#define FR_WO    384
#define FR_WVAL  512
#define FR_WOFF  640
#define FR_WATTN 768
#define FR_WOUT  832
#define FR_W1    960
#define FR_W2    1472
#define FR_TOTAL 1984

#define VGRID 2720   // value blocks (174080/64)
#define AGRID 640    // attn blocks (8*8*10, 32 q-rows each)
#define TGRID 3360   // VGRID + AGRID; attn interleaved: bid%5==4 && bid<3200

// ---------------------------------------------------------------------------
// Pack all weights fp32 [N][K] -> bf16 MFMA B-fragment layout. 1 wave = 1 frag.
// ---------------------------------------------------------------------------
__global__ __launch_bounds__(256) void pack_weights(
    const float* __restrict__ wq, const float* __restrict__ wk,
    const float* __restrict__ wv, const float* __restrict__ wo,
    const float* __restrict__ wval, const float* __restrict__ woff,
    const float* __restrict__ wattn, const float* __restrict__ wout,
    const float* __restrict__ w1, const float* __restrict__ w2,
    __bf16* __restrict__ Bpk)
{
  const int gw = (int)((blockIdx.x * blockDim.x + threadIdx.x) >> 6);
  const int lane = threadIdx.x & 63;
  if (gw >= FR_TOTAL) return;
  const float* W; int KT, base;
  if      (gw < FR_WK)   { W = wq;    KT = 8;  base = FR_WQ; }
  else if (gw < FR_WV)   { W = wk;    KT = 8;  base = FR_WK; }
  else if (gw < FR_WO)   { W = wv;    KT = 8;  base = FR_WV; }
  else if (gw < FR_WVAL) { W = wo;    KT = 8;  base = FR_WO; }
  else if (gw < FR_WOFF) { W = wval;  KT = 8;  base = FR_WVAL; }
  else if (gw < FR_WATTN){ W = woff;  KT = 8;  base = FR_WOFF; }
  else if (gw < FR_WOUT) { W = wattn; KT = 8;  base = FR_WATTN; }
  else if (gw < FR_W1)   { W = wout;  KT = 8;  base = FR_WOUT; }
  else if (gw < FR_W2)   { W = w1;    KT = 8;  base = FR_W1; }
  else                   { W = w2;    KT = 32; base = FR_W2; }
  const int f = gw - base;
  const int nf = f / KT, kt = f % KT;
  const int col = nf * 16 + (lane & 15);
  const int k0 = kt * 32 + (lane >> 4) * 8;
  const int K = KT * 32;
  const float4 a = *reinterpret_cast<const float4*>(W + (size_t)col * K + k0);
  const float4 b = *reinterpret_cast<const float4*>(W + (size_t)col * K + k0 + 4);
  bf16x8_t p = { (__bf16)a.x, (__bf16)a.y, (__bf16)a.z, (__bf16)a.w,
                 (__bf16)b.x, (__bf16)b.y, (__bf16)b.z, (__bf16)b.w };
  *reinterpret_cast<bf16x8_t*>(Bpk + ((size_t)gw * 64 + lane) * 8) = p;
}

// ---------------------------------------------------------------------------
// Small-GEMM body: BM=64, BN=128, 256 thr. Full 256-K chunk in swizzled LDS,
// 1 barrier per chunk. B direct from packed-fragment global. fp32 out.
// ---------------------------------------------------------------------------
template<int KT, bool RELU>
__device__ __forceinline__ void gemmS_body(
    __bf16* As,
    const float* __restrict__ A, const float* __restrict__ A2,
    const __bf16* __restrict__ Wp, const float* __restrict__ bias,
    float* __restrict__ out, int M, int N, int m0, int n0)
{
  const int tid = threadIdx.x;
  const int w = tid >> 6, lane = tid & 63;
  const int wm = w >> 1, wn = w & 1;
  const int fr = lane & 15, fq = lane >> 4;
  constexpr int K = KT * 32;

  float bld[4];
  #pragma unroll
  for (int n = 0; n < 4; ++n) bld[n] = bias[n0 + wn * 64 + n * 16 + fr];

  f32x4_t acc[2][4];
  const f32x4_t zz = {0.f, 0.f, 0.f, 0.f};
  #pragma unroll
  for (int m = 0; m < 2; ++m)
    #pragma unroll
    for (int n = 0; n < 4; ++n) acc[m][n] = zz;

  #pragma unroll
  for (int kc = 0; kc < KT / 8; ++kc) {
    if (kc) __syncthreads();
    #pragma unroll
    for (int rnd = 0; rnd < 2; ++rnd) {
      float4 pa[8];
      #pragma unroll
      for (int j = 0; j < 8; ++j) {
        const int row = m0 + w * 16 + rnd * 8 + j;
        const int ar = (row < M) ? row : (M - 1);
        pa[j] = *reinterpret_cast<const float4*>(A + (size_t)ar * K + kc * 256 + lane * 4);
        if (A2) {
          const float4 c = *reinterpret_cast<const float4*>(A2 + (size_t)ar * K + kc * 256 + lane * 4);
          pa[j].x += c.x; pa[j].y += c.y; pa[j].z += c.z; pa[j].w += c.w;
        }
      }
      #pragma unroll
      for (int j = 0; j < 8; ++j)
        *reinterpret_cast<bf16x4_t*>(lds_bf16(As, w * 16 + rnd * 8 + j, lane >> 1, (lane & 1) * 4)) =
            bf16x4_t{ (__bf16)pa[j].x, (__bf16)pa[j].y, (__bf16)pa[j].z, (__bf16)pa[j].w };
    }
    __syncthreads();
    #pragma unroll
    for (int kt2 = 0; kt2 < 8; ++kt2) {
      const int kt = kc * 8 + kt2;
      bf16x8_t bfr[4];
      #pragma unroll
      for (int n = 0; n < 4; ++n)
        bfr[n] = *reinterpret_cast<const bf16x8_t*>(
            Wp + (size_t)(((n0 >> 4) + wn * 4 + n) * KT + kt) * 512 + (size_t)lane * 8);
      bf16x8_t af[2];
      #pragma unroll
      for (int m = 0; m < 2; ++m)
        af[m] = *reinterpret_cast<const bf16x8_t*>(
            lds_bf16(As, wm * 32 + m * 16 + fr, kt2 * 4 + fq, 0));
      #pragma unroll
      for (int m = 0; m < 2; ++m)
        #pragma unroll
        for (int n = 0; n < 4; ++n)
          acc[m][n] = __builtin_amdgcn_mfma_f32_16x16x32_bf16(af[m], bfr[n], acc[m][n], 0, 0, 0);
    }
  }

  #pragma unroll
  for (int m = 0; m < 2; ++m) {
    const int row = m0 + wm * 32 + m * 16 + fq * 4;
    #pragma unroll
    for (int n = 0; n < 4; ++n) {
      const int col = n0 + wn * 64 + n * 16 + fr;
      #pragma unroll
      for (int j = 0; j < 4; ++j) {
        if (row + j < M) {
          float v = acc[m][n][j] + bld[n];
          if (RELU) v = fmaxf(v, 0.f);
          out[(size_t)(row + j) * N + col] = v;
        }
      }
    }
  }
}

template<int KT, bool RELU>
__global__ __launch_bounds__(256) void gemm64(
    const float* __restrict__ A, const float* __restrict__ A2,
    const __bf16* __restrict__ Wp, const float* __restrict__ bias,
    float* __restrict__ out, int M, int N)
{
  __shared__ __bf16 As[64 * 256];
  gemmS_body<KT, RELU>(As, A, A2, Wp, bias, out, M, N, blockIdx.y * 64, blockIdx.x * 128);
}

// Fused q/k/v projections: blockIdx.x 0..5 -> (sel = x>>1, n0 = (x&1)*128)
__global__ __launch_bounds__(256) void gemm_qkv(
    const float* __restrict__ tgt, const float* __restrict__ qpos,
    const __bf16* __restrict__ Bpk,
    const float* __restrict__ bq, const float* __restrict__ bk, const float* __restrict__ bv,
    float* __restrict__ qhb, float* __restrict__ khb, float* __restrict__ vhb, int M)
{
  __shared__ __bf16 As[64 * 256];
  const int sel = blockIdx.x >> 1;
  const int n0 = (blockIdx.x & 1) * 128;
  const __bf16* Wp; const float* bias; float* out; const float* A2;
  if (sel == 0)      { Wp = Bpk + (size_t)FR_WQ * 512; bias = bq; out = qhb; A2 = qpos; }
  else if (sel == 1) { Wp = Bpk + (size_t)FR_WK * 512; bias = bk; out = khb; A2 = qpos; }
  else               { Wp = Bpk + (size_t)FR_WV * 512; bias = bv; out = vhb; A2 = nullptr; }
  gemmS_body<8, false>(As, tgt, A2, Wp, bias, out, M, 256, blockIdx.y * 64, n0);
}

// Fused offset + attention-logit projections: blockIdx.x 0,1 -> w_off; 2 -> w_attn
__global__ __launch_bounds__(256) void gemm_offattn(
    const float* __restrict__ tgt1, const float* __restrict__ qpos,
    const __bf16* __restrict__ Bpk,
    const float* __restrict__ b_off, const float* __restrict__ b_attn,
    float* __restrict__ offb, float* __restrict__ awlb, int M)
{
  __shared__ __bf16 As[64 * 256];
  const int bx = blockIdx.x;
  if (bx < 2)
    gemmS_body<8, false>(As, tgt1, qpos, Bpk + (size_t)FR_WOFF * 512, b_off, offb,
                         M, 256, blockIdx.y * 64, bx * 128);
  else
    gemmS_body<8, false>(As, tgt1, qpos, Bpk + (size_t)FR_WATTN * 512, b_attn, awlb,
                         M, 128, blockIdx.y * 64, 0);
}

// ---------------------------------------------------------------------------
// GEMM (BM=32 x BN=256) + residual + LayerNorm fused epilogue. fp32 out.
// ---------------------------------------------------------------------------
template<int KT>
__global__ __launch_bounds__(256) void gemm_ln(
    const float* __restrict__ A, const __bf16* __restrict__ Wp,
    const float* __restrict__ bias, const float* __restrict__ X,
    const float* __restrict__ g, const float* __restrict__ beta,
    float* __restrict__ out, int M)
{
  __shared__ __bf16 As[32 * 256];
  __shared__ float R[32][260];
  const int tid = threadIdx.x;
  const int w = tid >> 6, lane = tid & 63;
  const int wm = w >> 1, wn = w & 1;
  const int fr = lane & 15, fq = lane >> 4;
  const int m0 = blockIdx.x * 32;
  constexpr int K = KT * 32;

  float bld[8];
  #pragma unroll
  for (int n = 0; n < 8; ++n) bld[n] = bias[wn * 128 + n * 16 + fr];

  f32x4_t acc[8];
  const f32x4_t zz = {0.f, 0.f, 0.f, 0.f};
  #pragma unroll
  for (int n = 0; n < 8; ++n) acc[n] = zz;

  #pragma unroll
  for (int kc = 0; kc < KT / 8; ++kc) {
    if (kc) __syncthreads();
    {
      float4 pa[8];
      #pragma unroll
      for (int j = 0; j < 8; ++j) {
        const int row = m0 + w * 8 + j;
        const int ar = (row < M) ? row : (M - 1);
        pa[j] = *reinterpret_cast<const float4*>(A + (size_t)ar * K + kc * 256 + lane * 4);
      }
      #pragma unroll
      for (int j = 0; j < 8; ++j)
        *reinterpret_cast<bf16x4_t*>(lds_bf16(As, w * 8 + j, lane >> 1, (lane & 1) * 4)) =
            bf16x4_t{ (__bf16)pa[j].x, (__bf16)pa[j].y, (__bf16)pa[j].z, (__bf16)pa[j].w };
    }
    __syncthreads();
    #pragma unroll
    for (int kt2 = 0; kt2 < 8; ++kt2) {
      const int kt = kc * 8 + kt2;
      bf16x8_t bfr[8];
      #pragma unroll
      for (int n = 0; n < 8; ++n)
        bfr[n] = *reinterpret_cast<const bf16x8_t*>(
            Wp + (size_t)((wn * 8 + n) * KT + kt) * 512 + (size_t)lane * 8);
      const bf16x8_t af = *reinterpret_cast<const bf16x8_t*>(
          lds_bf16(As, wm * 16 + fr, kt2 * 4 + fq, 0));
      #pragma unroll
      for (int n = 0; n < 8; ++n)
        acc[n] = __builtin_amdgcn_mfma_f32_16x16x32_bf16(af, bfr[n], acc[n], 0, 0, 0);
    }
  }

  #pragma unroll
  for (int n = 0; n < 8; ++n)
    #pragma unroll
    for (int j = 0; j < 4; ++j)
      R[wm * 16 + fq * 4 + j][wn * 128 + n * 16 + fr] = acc[n][j] + bld[n];
  __syncthreads();

  const int r = tid >> 3, p = tid & 7;
  const int grow = m0 + r;
  const int ar = (grow < M) ? grow : (M - 1);
  float4 vbuf[8];
  float sum = 0.f, sq = 0.f;
  #pragma unroll
  for (int i = 0; i < 8; ++i) {
    float4 v = *reinterpret_cast<const float4*>(&R[r][p * 32 + i * 4]);
    const float4 x = *reinterpret_cast<const float4*>(X + (size_t)ar * 256 + p * 32 + i * 4);
    v.x += x.x; v.y += x.y; v.z += x.z; v.w += x.w;
    vbuf[i] = v;
    sum += v.x + v.y + v.z + v.w;
    sq += v.x * v.x + v.y * v.y + v.z * v.z + v.w * v.w;
  }
  sum += __shfl_xor(sum, 1); sum += __shfl_xor(sum, 2); sum += __shfl_xor(sum, 4);
  sq  += __shfl_xor(sq, 1);  sq  += __shfl_xor(sq, 2);  sq  += __shfl_xor(sq, 4);
  const float mean = sum * (1.f / 256.f);
  const float var = sq * (1.f / 256.f) - mean * mean;
  const float sc = rsqrtf(var + LN_EPS);
  if (grow < M) {
    #pragma unroll
    for (int i = 0; i < 8; ++i) {
      const float4 gg = *reinterpret_cast<const float4*>(g + p * 32 + i * 4);
      const float4 bb = *reinterpret_cast<const float4*>(beta + p * 32 + i * 4);
      float4 o;
      o.x = (vbuf[i].x - mean) * sc * gg.x + bb.x;
      o.y = (vbuf[i].y - mean) * sc * gg.y + bb.y;
      o.z = (vbuf[i].z - mean) * sc * gg.z + bb.z;
      o.w = (vbuf[i].w - mean) * sc * gg.w + bb.w;
      *reinterpret_cast<float4*>(out + (size_t)grow * 256 + p * 32 + i * 4) = o;
    }
  }
}

// ---------------------------------------------------------------------------
// MEGA: value projection + self-attention, interleaved block mapping.
// Attn blocks now cover 32 q-rows each (K/V staged once per 32 rows).
// R12-proven LDS config: K stride 38, V stride 36, launch_bounds(256,3).
// ---------------------------------------------------------------------------
struct AttnSh { u16 Kb[304][38]; u16 Vb[304][36]; float pbuf[4][304]; };
struct ValSh  { __bf16 As[64 * 256]; };

__global__ __launch_bounds__(256, 3) void val_attn(
    const float* __restrict__ src, const __bf16* __restrict__ Bpk,
    const float* __restrict__ b_val, bf16* __restrict__ valb,
    const float* __restrict__ qh, const float* __restrict__ kh,
    const float* __restrict__ vh, float* __restrict__ sa)
{
  __shared__ union { AttnSh a; ValSh v; } sh;
  const int tid = threadIdx.x;
  const int w = tid >> 6, lane = tid & 63;
  const int fr = lane & 15, fq = lane >> 4;

  const int bid = blockIdx.x;
  const bool is_attn = (bid < 3200) && (bid % 5 == 4);
  const int wid = is_attn ? (bid / 5)
                          : (bid < 3200 ? (bid / 5) * 4 + (bid % 5) : 2560 + (bid - 3200));

  if (!is_attn) {
    // ---------------- value projection ----------------
    __bf16* As = sh.v.As;
    const __bf16* Wp = Bpk + (size_t)FR_WVAL * 512;
    const size_t m0 = (size_t)wid * 64;

    float bld[4];
    #pragma unroll
    for (int n = 0; n < 4; ++n) bld[n] = b_val[w * 64 + n * 16 + fr];

    // stage: all 16 loads in flight, then LDS writes (swizzled)
    const float* g = src + (m0 + (size_t)w * 16) * 256 + lane * 4;
    float4 p[16];
    #pragma unroll
    for (int j = 0; j < 16; ++j)
      p[j] = *reinterpret_cast<const float4*>(g + (size_t)j * 256);
    #pragma unroll
    for (int j = 0; j < 16; ++j)
      *reinterpret_cast<bf16x4_t*>(lds_bf16(As, w * 16 + j, lane >> 1, (lane & 1) * 4)) =
          bf16x4_t{ (__bf16)p[j].x, (__bf16)p[j].y, (__bf16)p[j].z, (__bf16)p[j].w };

    f32x4_t acc[4][4];
    const f32x4_t zz = {0.f, 0.f, 0.f, 0.f};
    #pragma unroll
    for (int m = 0; m < 4; ++m)
      #pragma unroll
      for (int n = 0; n < 4; ++n) acc[m][n] = zz;

    const __bf16* wpl = Wp + (size_t)lane * 8;
    __syncthreads();

    #pragma unroll
    for (int kt = 0; kt < 8; ++kt) {
      bf16x8_t bfr[4];
      #pragma unroll
      for (int n = 0; n < 4; ++n)
        bfr[n] = *reinterpret_cast<const bf16x8_t*>(wpl + (size_t)((w * 4 + n) * 8 + kt) * 512);
      bf16x8_t af[4];
      #pragma unroll
      for (int m = 0; m < 4; ++m)
        af[m] = *reinterpret_cast<const bf16x8_t*>(
            lds_bf16(As, m * 16 + fr, kt * 4 + fq, 0));
      #pragma unroll
      for (int m = 0; m < 4; ++m)
        #pragma unroll
        for (int n = 0; n < 4; ++n)
          acc[m][n] = __builtin_amdgcn_mfma_f32_16x16x32_bf16(af[m], bfr[n], acc[m][n], 0, 0, 0);
    }

    __syncthreads();
    #pragma unroll
    for (int m = 0; m < 4; ++m)
      #pragma unroll
      for (int n = 0; n < 4; ++n)
        #pragma unroll
        for (int j = 0; j < 4; ++j)
          *lds_bf16(As, m * 16 + fq * 4 + j, w * 8 + n * 2 + (fr >> 3), fr & 7) =
              (__bf16)(acc[m][n][j] + bld[n]);
    __syncthreads();
    #pragma unroll
    for (int i = 0; i < 8; ++i) {
      const int pby = i * 4096 + tid * 16;
      const int row = pby >> 9;
      const int chunk = (pby & 511) >> 4;
      const bf16x8_t v = *reinterpret_cast<const bf16x8_t*>(lds_bf16(As, row, chunk, 0));
      *reinterpret_cast<bf16x8_t*>(
          reinterpret_cast<char*>(valb + (m0 + row) * 256) + (pby & 511)) = v;
    }
    return;
  }

  // ---------------- self-attention (32 q-rows per block) ----------------
  auto& Kb = sh.a.Kb;
  auto& Vb = sh.a.Vb;
  auto& pbuf = sh.a.pbuf;
  const int qt2 = wid % 10;
  const int bh = wid / 10;
  const int h = bh & 7, b = bh >> 3;
  const size_t base = ((size_t)b * Qq) * Cc + h * DHh;

  for (int idx = tid; idx < 304 * 16; idx += 256) {
    const int k = idx >> 4, dd = idx & 15;
    u32 kw = 0, vw = 0;
    if (k < Qq) {
      const float2 kf = *reinterpret_cast<const float2*>(kh + base + (size_t)k * Cc + 2 * dd);
      const float2 vf = *reinterpret_cast<const float2*>(vh + base + (size_t)k * Cc + 2 * dd);
      kw = (u32)f2bf(kf.x * 0.17677669529663687f) |
           ((u32)f2bf(kf.y * 0.17677669529663687f) << 16);
      vw = (u32)f2bf(vf.x) | ((u32)f2bf(vf.y) << 16);
    }
    *reinterpret_cast<u32*>(&Kb[k][2 * dd]) = kw;
    *reinterpret_cast<u32*>(&Vb[k][2 * dd]) = vw;
  }
  __syncthreads();

  const int qtr = lane >> 4, dp = lane & 15;

  for (int rr = 0; rr < 8; ++rr) {
    const int q0 = qt2 * 32 + w * 8 + rr;
    const int q = (q0 < Qq) ? q0 : (Qq - 1);
    const float* qp = qh + base + (size_t)q * Cc;
    float qv[32];
    #pragma unroll
    for (int i = 0; i < 8; ++i) {
      const float4 t = reinterpret_cast<const float4*>(qp)[i];
      qv[i*4+0] = t.x; qv[i*4+1] = t.y; qv[i*4+2] = t.z; qv[i*4+3] = t.w;
    }

    float e[5];
    float mx = -1e30f;
    #pragma unroll
    for (int i = 0; i < 5; ++i) {
      const int k = lane + i * 64;
      if (k < Qq) {
        const u32* kp = reinterpret_cast<const u32*>(&Kb[k][0]);
        float s = 0.f;
        #pragma unroll
        for (int d2 = 0; d2 < 16; ++d2) {
          const u32 kw = kp[d2];
          s = fmaf(qv[2*d2], bfbits_lo(kw), s);
          s = fmaf(qv[2*d2+1], bfbits_hi(kw), s);
        }
        e[i] = s;
      } else {
        e[i] = -1e30f;
      }
      mx = fmaxf(mx, e[i]);
    }
    #pragma unroll
    for (int o = 32; o; o >>= 1) mx = fmaxf(mx, __shfl_xor(mx, o));
    float ssum = 0.f;
    #pragma unroll
    for (int i = 0; i < 5; ++i) { e[i] = __expf(e[i] - mx); ssum += e[i]; }
    #pragma unroll
    for (int o = 32; o; o >>= 1) ssum += __shfl_xor(ssum, o);
    const float inv = 1.f / ssum;
    #pragma unroll
    for (int i = 0; i < 5; ++i) {
      const int k = lane + i * 64;
      if (k < 304) pbuf[w][k] = (k < Qq) ? e[i] * inv : 0.f;
    }
    __syncthreads();

    float accA = 0.f, accB = 0.f;
    const float* prow = pbuf[w] + qtr * 76;
    #pragma unroll 4
    for (int j4 = 0; j4 < 19; ++j4) {
      const float4 pv4 = *reinterpret_cast<const float4*>(prow + j4 * 4);
      const int kb = qtr * 76 + j4 * 4;
      const u32 v0 = *reinterpret_cast<const u32*>(&Vb[kb + 0][2*dp]);
      const u32 v1 = *reinterpret_cast<const u32*>(&Vb[kb + 1][2*dp]);
      const u32 v2 = *reinterpret_cast<const u32*>(&Vb[kb + 2][2*dp]);
      const u32 v3 = *reinterpret_cast<const u32*>(&Vb[kb + 3][2*dp]);
      accA = fmaf(pv4.x, bfbits_lo(v0), accA); accB = fmaf(pv4.x, bfbits_hi(v0), accB);
      accA = fmaf(pv4.y, bfbits_lo(v1), accA); accB = fmaf(pv4.y, bfbits_hi(v1), accB);
      accA = fmaf(pv4.z, bfbits_lo(v2), accA); accB = fmaf(pv4.z, bfbits_hi(v2), accB);
      accA = fmaf(pv4.w, bfbits_lo(v3), accA); accB = fmaf(pv4.w, bfbits_hi(v3), accB);
    }
    accA += __shfl_xor(accA, 16); accA += __shfl_xor(accA, 32);
    accB += __shfl_xor(accB, 16); accB += __shfl_xor(accB, 32);
    if (q0 < Qq && lane < 16) {
      float2 st; st.x = accA; st.y = accB;
      *reinterpret_cast<float2*>(sa + base + (size_t)q * Cc + 2 * dp) = st;
    }
    __syncthreads();
  }
}

// ---------------------------------------------------------------------------
// Deformable sampling: one wave per (b,q,h). lane = pt*16 + dp.
// ---------------------------------------------------------------------------
__global__ __launch_bounds__(256) void deform_kernel(
    const float* __restrict__ offb, const float* __restrict__ awl,
    const float* __restrict__ refp, const bf16* __restrict__ value,
    float* __restrict__ accp)
{
  const int gw = (int)((blockIdx.x * (size_t)blockDim.x + threadIdx.x) >> 6);
  if (gw >= Bb * Qq * NHh) return;
  const int lane = threadIdx.x & 63;
  const int h = gw % NHh;
  const int t = gw / NHh;
  const int qi = t % Qq;
  const int b = t / Qq;
  const int pt = lane >> 4;
  const int dp = lane & 15;

  const float* awp = awl + (size_t)(b * Qq + qi) * 128 + h * 16;
  float e[16];
  {
    const float4 e0 = *reinterpret_cast<const float4*>(awp + 0);
    const float4 e1 = *reinterpret_cast<const float4*>(awp + 4);
    const float4 e2 = *reinterpret_cast<const float4*>(awp + 8);
    const float4 e3 = *reinterpret_cast<const float4*>(awp + 12);
    e[0]=e0.x; e[1]=e0.y; e[2]=e0.z; e[3]=e0.w;
    e[4]=e1.x; e[5]=e1.y; e[6]=e1.z; e[7]=e1.w;
    e[8]=e2.x; e[9]=e2.y; e[10]=e2.z; e[11]=e2.w;
    e[12]=e3.x; e[13]=e3.y; e[14]=e3.z; e[15]=e3.w;
  }
  float mx = -1e30f;
  #pragma unroll
  for (int i = 0; i < 16; ++i) mx = fmaxf(mx, e[i]);
  float s = 0.f;
  #pragma unroll
  for (int i = 0; i < 16; ++i) { e[i] = __expf(e[i] - mx); s += e[i]; }
  const float inv = 1.f / s;

  const float* offp = offb + (size_t)(b * Qq + qi) * Cc + h * 32;
  const float* rp = refp + (size_t)(b * Qq + qi) * 8;
  const int lH[4] = {128, 64, 32, 16};
  const int lW[4] = {128, 64, 32, 16};
  const int lS[4] = {0, 16384, 20480, 21504};

  const u16* vbase = reinterpret_cast<const u16*>(value) + (size_t)h * 32 + 2 * dp;

  float accx = 0.f, accy = 0.f;
  #pragma unroll
  for (int l = 0; l < 4; ++l) {
    const int Hl = lH[l], Wl = lW[l], st = lS[l];
    const float rx = rp[l * 2 + 0], ry = rp[l * 2 + 1];
    const float ax = offp[l * 8 + pt * 2 + 0];
    const float ay = offp[l * 8 + pt * 2 + 1];
    const float x = (rx + ax / (float)Wl) * (float)Wl - 0.5f;
    const float y = (ry + ay / (float)Hl) * (float)Hl - 0.5f;
    const float x0f = floorf(x), y0f = floorf(y);
    const float wx = x - x0f, wy = y - y0f;
    const int x0 = (int)x0f, y0 = (int)y0f;
    const float wp = e[l * 4 + pt] * inv;
    #pragma unroll
    for (int dy = 0; dy < 2; ++dy) {
      #pragma unroll
      for (int dx = 0; dx < 2; ++dx) {
        const int xi = x0 + dx, yi = y0 + dy;
        if (xi >= 0 && xi < Wl && yi >= 0 && yi < Hl) {
          const float wgt = wp * (dx ? wx : 1.f - wx) * (dy ? wy : 1.f - wy);
          const u32 v = *reinterpret_cast<const u32*>(
              vbase + (size_t)(b * (size_t)Ss + st + yi * Wl + xi) * Cc);
          accx = fmaf(wgt, bfbits_lo(v), accx);
          accy = fmaf(wgt, bfbits_hi(v), accy);
        }
      }
    }
  }
  accx += __shfl_xor(accx, 16); accx += __shfl_xor(accx, 32);
  accy += __shfl_xor(accy, 16); accy += __shfl_xor(accy, 32);
  if (lane < 16) {
    float2 st2; st2.x = accx; st2.y = accy;
    *reinterpret_cast<float2*>(accp + (size_t)(b * Qq + qi) * Cc + h * 32 + 2 * dp) = st2;
  }
}

// ---------------------------------------------------------------------------
extern "C" void kernel_launch(void* const* d_in, const int* in_sizes, int n_in,
                              void* d_out, int out_size, void* d_ws, size_t ws_size,
                              hipStream_t stream) {
  const float* tgt   = (const float*)d_in[0];
  const float* qpos  = (const float*)d_in[2];
  const float* refp  = (const float*)d_in[3];
  const float* src   = (const float*)d_in[4];
  const float* wq = (const float*)d_in[8];   const float* bq = (const float*)d_in[9];
  const float* wk = (const float*)d_in[10];  const float* bk = (const float*)d_in[11];
  const float* wv = (const float*)d_in[12];  const float* bv = (const float*)d_in[13];
  const float* wo = (const float*)d_in[14];  const float* bo = (const float*)d_in[15];
  const float* w_off = (const float*)d_in[16];  const float* b_off = (const float*)d_in[17];
  const float* w_attn = (const float*)d_in[18]; const float* b_attn = (const float*)d_in[19];
  const float* w_val = (const float*)d_in[20];  const float* b_val = (const float*)d_in[21];
  const float* w_out = (const float*)d_in[22];  const float* b_out = (const float*)d_in[23];
  const float* w1 = (const float*)d_in[24];  const float* b1 = (const float*)d_in[25];
  const float* w2 = (const float*)d_in[26];  const float* b2 = (const float*)d_in[27];
  const float* ln2g = (const float*)d_in[28]; const float* ln2b = (const float*)d_in[29];
  const float* ln1g = (const float*)d_in[30]; const float* ln1b = (const float*)d_in[31];
  const float* ln3g = (const float*)d_in[32]; const float* ln3b = (const float*)d_in[33];

  float* fws = (float*)d_ws;
  const size_t NBQ = (size_t)Bb * Qq * Cc;  // 614400
  float* qhb  = fws;
  float* khb  = qhb  + NBQ;
  float* vhb  = khb  + NBQ;
  float* sab  = vhb  + NBQ;
  float* tgt1 = sab  + NBQ;
  float* offb = tgt1 + NBQ;
  float* accb = offb + NBQ;
  float* t2nb = accb + NBQ;
  float* awlb = t2nb + NBQ;                       // 2400*128
  float* ffhb = awlb + (size_t)Bb * Qq * 128;     // 2400*1024
  bf16*  valb = (bf16*)(ffhb + (size_t)Bb * Qq * DFFf);   // 174080*256 bf16
  __bf16* Bpk = (__bf16*)(valb + (size_t)Bb * Ss * Cc);   // 1984*512 bf16

  const int MQ = Bb * Qq;          // 2400
  const int MT = (MQ + 63) / 64;   // 38
  const int MT2 = (MQ + 31) / 32;  // 75
  dim3 blk(256, 1, 1);

  pack_weights<<<dim3((FR_TOTAL + 3) / 4), blk, 0, stream>>>(
      wq, wk, wv, wo, w_val, w_off, w_attn, w_out, w1, w2, Bpk);

  gemm_qkv<<<dim3(6, MT), blk, 0, stream>>>(tgt, qpos, Bpk, bq, bk, bv, qhb, khb, vhb, MQ);

  // value projection (2720 blocks) interleaved with self-attention (640)
  val_attn<<<dim3(TGRID), blk, 0, stream>>>(
      src, Bpk, b_val, valb, qhb, khb, vhb, sab);

  // wo projection + residual(tgt) + ln2 -> tgt1
  gemm_ln<8><<<dim3(MT2), blk, 0, stream>>>(
      sab, Bpk + (size_t)FR_WO * 512, bo, tgt, ln2g, ln2b, tgt1, MQ);

  gemm_offattn<<<dim3(3, MT), blk, 0, stream>>>(tgt1, qpos, Bpk, b_off, b_attn, offb, awlb, MQ);

  deform_kernel<<<dim3(Bb * Qq * NHh / 4), blk, 0, stream>>>(offb, awlb, refp, valb, accb);

  // w_out projection + residual(tgt1) + ln1 -> t2nb
  gemm_ln<8><<<dim3(MT2), blk, 0, stream>>>(
      accb, Bpk + (size_t)FR_WOUT * 512, b_out, tgt1, ln1g, ln1b, t2nb, MQ);

  // FFN
  gemm64<8, true><<<dim3(8, MT), blk, 0, stream>>>(t2nb, nullptr, Bpk + (size_t)FR_W1 * 512, b1, ffhb, MQ, DFFf);
  gemm_ln<32><<<dim3(MT2), blk, 0, stream>>>(
      ffhb, Bpk + (size_t)FR_W2 * 512, b2, t2nb, ln3g, ln3b, (float*)d_out, MQ);
}

// Round 18
// 196.867 us; speedup vs baseline: 1.0625x; 1.0625x over previous
//
#include <hip/hip_runtime.h>
#include <hip/hip_bf16.h>
#include <math.h>

#define Bb   8
#define Qq   300
#define Cc   256
#define NHh  8
#define DHh  32
#define Ss   21760
#define DFFf 1024
#define LN_EPS 1e-5f

typedef __hip_bfloat16 bf16;
typedef unsigned short u16;
typedef unsigned int u32;
typedef __bf16 bf16x8_t __attribute__((ext_vector_type(8)));
typedef __bf16 bf16x4_t __attribute__((ext_vector_type(4)));
typedef float f32x4_t __attribute__((ext_vector_type(4)));

__device__ inline u16 f2bf(float f) {
  union { float f; u32 u; } v; v.f = f;
  u32 u = v.u + 0x7fffu + ((v.u >> 16) & 1u);
  return (u16)(u >> 16);
}
__device__ inline float bfbits_lo(u32 w) {
  union { u32 u; float f; } v; v.u = w << 16;
  return v.f;
}
__device__ inline float bfbits_hi(u32 w) {
  union { u32 u; float f; } v; v.u = w & 0xffff0000u;
  return v.f;
}

// LDS A-tile: packed [R][256] bf16 with 16B-chunk XOR swizzle (T2):
// physical chunk = logical chunk ^ (row & 7).
__device__ inline __bf16* lds_bf16(__bf16* base, int row, int chunk, int sub) {
  return base + (row << 8) + (((chunk ^ (row & 7)) << 3) + sub);
}

// Packed-weight fragment bases (in 512-elem frag units).
#define FR_WQ    0
#define FR_WK    128
#define FR_WV    256
#define FR_WO    384
#define FR_WVAL  512
#define FR_WOFF  640
#define FR_WATTN 768
#define FR_WOUT  832
#define FR_W1    960
#define FR_W2    1472
#define FR_TOTAL 1984

#define VGRID 2720   // value blocks (174080/64)
#define AGRID 1216   // attn blocks  (8*8*19, 16 q-rows each)
#define TGRID 3936   // VGRID + AGRID; attn interleaved: bid%3==2 && bid<3648

// ---------------------------------------------------------------------------
// Pack all weights fp32 [N][K] -> bf16 MFMA B-fragment layout. 1 wave = 1 frag.
// ---------------------------------------------------------------------------
__global__ __launch_bounds__(256) void pack_weights(
    const float* __restrict__ wq, const float* __restrict__ wk,
    const float* __restrict__ wv, const float* __restrict__ wo,
    const float* __restrict__ wval, const float* __restrict__ woff,
    const float* __restrict__ wattn, const float* __restrict__ wout,
    const float* __restrict__ w1, const float* __restrict__ w2,
    __bf16* __restrict__ Bpk)
{
  const int gw = (int)((blockIdx.x * blockDim.x + threadIdx.x) >> 6);
  const int lane = threadIdx.x & 63;
  if (gw >= FR_TOTAL) return;
  const float* W; int KT, base;
  if      (gw < FR_WK)   { W = wq;    KT = 8;  base = FR_WQ; }
  else if (gw < FR_WV)   { W = wk;    KT = 8;  base = FR_WK; }
  else if (gw < FR_WO)   { W = wv;    KT = 8;  base = FR_WV; }
  else if (gw < FR_WVAL) { W = wo;    KT = 8;  base = FR_WO; }
  else if (gw < FR_WOFF) { W = wval;  KT = 8;  base = FR_WVAL; }
  else if (gw < FR_WATTN){ W = woff;  KT = 8;  base = FR_WOFF; }
  else if (gw < FR_WOUT) { W = wattn; KT = 8;  base = FR_WATTN; }
  else if (gw < FR_W1)   { W = wout;  KT = 8;  base = FR_WOUT; }
  else if (gw < FR_W2)   { W = w1;    KT = 8;  base = FR_W1; }
  else                   { W = w2;    KT = 32; base = FR_W2; }
  const int f = gw - base;
  const int nf = f / KT, kt = f % KT;
  const int col = nf * 16 + (lane & 15);
  const int k0 = kt * 32 + (lane >> 4) * 8;
  const int K = KT * 32;
  const float4 a = *reinterpret_cast<const float4*>(W + (size_t)col * K + k0);
  const float4 b = *reinterpret_cast<const float4*>(W + (size_t)col * K + k0 + 4);
  bf16x8_t p = { (__bf16)a.x, (__bf16)a.y, (__bf16)a.z, (__bf16)a.w,
                 (__bf16)b.x, (__bf16)b.y, (__bf16)b.z, (__bf16)b.w };
  *reinterpret_cast<bf16x8_t*>(Bpk + ((size_t)gw * 64 + lane) * 8) = p;
}

// ---------------------------------------------------------------------------
// Small-GEMM body: BM=64, BN=128, 256 thr. Full 256-K chunk in swizzled LDS,
// 1 barrier per chunk. B direct from packed-fragment global. fp32 out.
// ---------------------------------------------------------------------------
template<int KT, bool RELU>
__device__ __forceinline__ void gemmS_body(
    __bf16* As,
    const float* __restrict__ A, const float* __restrict__ A2,
    const __bf16* __restrict__ Wp, const float* __restrict__ bias,
    float* __restrict__ out, int M, int N, int m0, int n0)
{
  const int tid = threadIdx.x;
  const int w = tid >> 6, lane = tid & 63;
  const int wm = w >> 1, wn = w & 1;
  const int fr = lane & 15, fq = lane >> 4;
  constexpr int K = KT * 32;

  float bld[4];
  #pragma unroll
  for (int n = 0; n < 4; ++n) bld[n] = bias[n0 + wn * 64 + n * 16 + fr];

  f32x4_t acc[2][4];
  const f32x4_t zz = {0.f, 0.f, 0.f, 0.f};
  #pragma unroll
  for (int m = 0; m < 2; ++m)
    #pragma unroll
    for (int n = 0; n < 4; ++n) acc[m][n] = zz;

  #pragma unroll
  for (int kc = 0; kc < KT / 8; ++kc) {
    if (kc) __syncthreads();
    #pragma unroll
    for (int rnd = 0; rnd < 2; ++rnd) {
      float4 pa[8];
      #pragma unroll
      for (int j = 0; j < 8; ++j) {
        const int row = m0 + w * 16 + rnd * 8 + j;
        const int ar = (row < M) ? row : (M - 1);
        pa[j] = *reinterpret_cast<const float4*>(A + (size_t)ar * K + kc * 256 + lane * 4);
        if (A2) {
          const float4 c = *reinterpret_cast<const float4*>(A2 + (size_t)ar * K + kc * 256 + lane * 4);
          pa[j].x += c.x; pa[j].y += c.y; pa[j].z += c.z; pa[j].w += c.w;
        }
      }
      #pragma unroll
      for (int j = 0; j < 8; ++j)
        *reinterpret_cast<bf16x4_t*>(lds_bf16(As, w * 16 + rnd * 8 + j, lane >> 1, (lane & 1) * 4)) =
            bf16x4_t{ (__bf16)pa[j].x, (__bf16)pa[j].y, (__bf16)pa[j].z, (__bf16)pa[j].w };
    }
    __syncthreads();
    #pragma unroll
    for (int kt2 = 0; kt2 < 8; ++kt2) {
      const int kt = kc * 8 + kt2;
      bf16x8_t bfr[4];
      #pragma unroll
      for (int n = 0; n < 4; ++n)
        bfr[n] = *reinterpret_cast<const bf16x8_t*>(
            Wp + (size_t)(((n0 >> 4) + wn * 4 + n) * KT + kt) * 512 + (size_t)lane * 8);
      bf16x8_t af[2];
      #pragma unroll
      for (int m = 0; m < 2; ++m)
        af[m] = *reinterpret_cast<const bf16x8_t*>(
            lds_bf16(As, wm * 32 + m * 16 + fr, kt2 * 4 + fq, 0));
      #pragma unroll
      for (int m = 0; m < 2; ++m)
        #pragma unroll
        for (int n = 0; n < 4; ++n)
          acc[m][n] = __builtin_amdgcn_mfma_f32_16x16x32_bf16(af[m], bfr[n], acc[m][n], 0, 0, 0);
    }
  }

  #pragma unroll
  for (int m = 0; m < 2; ++m) {
    const int row = m0 + wm * 32 + m * 16 + fq * 4;
    #pragma unroll
    for (int n = 0; n < 4; ++n) {
      const int col = n0 + wn * 64 + n * 16 + fr;
      #pragma unroll
      for (int j = 0; j < 4; ++j) {
        if (row + j < M) {
          float v = acc[m][n][j] + bld[n];
          if (RELU) v = fmaxf(v, 0.f);
          out[(size_t)(row + j) * N + col] = v;
        }
      }
    }
  }
}

template<int KT, bool RELU>
__global__ __launch_bounds__(256) void gemm64(
    const float* __restrict__ A, const float* __restrict__ A2,
    const __bf16* __restrict__ Wp, const float* __restrict__ bias,
    float* __restrict__ out, int M, int N)
{
  __shared__ __bf16 As[64 * 256];
  gemmS_body<KT, RELU>(As, A, A2, Wp, bias, out, M, N, blockIdx.y * 64, blockIdx.x * 128);
}

// Fused q/k/v projections: blockIdx.x 0..5 -> (sel = x>>1, n0 = (x&1)*128)
__global__ __launch_bounds__(256) void gemm_qkv(
    const float* __restrict__ tgt, const float* __restrict__ qpos,
    const __bf16* __restrict__ Bpk,
    const float* __restrict__ bq, const float* __restrict__ bk, const float* __restrict__ bv,
    float* __restrict__ qhb, float* __restrict__ khb, float* __restrict__ vhb, int M)
{
  __shared__ __bf16 As[64 * 256];
  const int sel = blockIdx.x >> 1;
  const int n0 = (blockIdx.x & 1) * 128;
  const __bf16* Wp; const float* bias; float* out; const float* A2;
  if (sel == 0)      { Wp = Bpk + (size_t)FR_WQ * 512; bias = bq; out = qhb; A2 = qpos; }
  else if (sel == 1) { Wp = Bpk + (size_t)FR_WK * 512; bias = bk; out = khb; A2 = qpos; }
  else               { Wp = Bpk + (size_t)FR_WV * 512; bias = bv; out = vhb; A2 = nullptr; }
  gemmS_body<8, false>(As, tgt, A2, Wp, bias, out, M, 256, blockIdx.y * 64, n0);
}

// Fused offset + attention-logit projections: blockIdx.x 0,1 -> w_off; 2 -> w_attn
__global__ __launch_bounds__(256) void gemm_offattn(
    const float* __restrict__ tgt1, const float* __restrict__ qpos,
    const __bf16* __restrict__ Bpk,
    const float* __restrict__ b_off, const float* __restrict__ b_attn,
    float* __restrict__ offb, float* __restrict__ awlb, int M)
{
  __shared__ __bf16 As[64 * 256];
  const int bx = blockIdx.x;
  if (bx < 2)
    gemmS_body<8, false>(As, tgt1, qpos, Bpk + (size_t)FR_WOFF * 512, b_off, offb,
                         M, 256, blockIdx.y * 64, bx * 128);
  else
    gemmS_body<8, false>(As, tgt1, qpos, Bpk + (size_t)FR_WATTN * 512, b_attn, awlb,
                         M, 128, blockIdx.y * 64, 0);
}

// ---------------------------------------------------------------------------
// GEMM (BM=32 x BN=256) + residual + LayerNorm fused epilogue. fp32 out.
// ---------------------------------------------------------------------------
template<int KT>
__global__ __launch_bounds__(256) void gemm_ln(
    const float* __restrict__ A, const __bf16* __restrict__ Wp,
    const float* __restrict__ bias, const float* __restrict__ X,
    const float* __restrict__ g, const float* __restrict__ beta,
    float* __restrict__ out, int M)
{
  __shared__ __bf16 As[32 * 256];
  __shared__ float R[32][260];
  const int tid = threadIdx.x;
  const int w = tid >> 6, lane = tid & 63;
  const int wm = w >> 1, wn = w & 1;
  const int fr = lane & 15, fq = lane >> 4;
  const int m0 = blockIdx.x * 32;
  constexpr int K = KT * 32;

  float bld[8];
  #pragma unroll
  for (int n = 0; n < 8; ++n) bld[n] = bias[wn * 128 + n * 16 + fr];

  f32x4_t acc[8];
  const f32x4_t zz = {0.f, 0.f, 0.f, 0.f};
  #pragma unroll
  for (int n = 0; n < 8; ++n) acc[n] = zz;

  #pragma unroll
  for (int kc = 0; kc < KT / 8; ++kc) {
    if (kc) __syncthreads();
    {
      float4 pa[8];
      #pragma unroll
      for (int j = 0; j < 8; ++j) {
        const int row = m0 + w * 8 + j;
        const int ar = (row < M) ? row : (M - 1);
        pa[j] = *reinterpret_cast<const float4*>(A + (size_t)ar * K + kc * 256 + lane * 4);
      }
      #pragma unroll
      for (int j = 0; j < 8; ++j)
        *reinterpret_cast<bf16x4_t*>(lds_bf16(As, w * 8 + j, lane >> 1, (lane & 1) * 4)) =
            bf16x4_t{ (__bf16)pa[j].x, (__bf16)pa[j].y, (__bf16)pa[j].z, (__bf16)pa[j].w };
    }
    __syncthreads();
    #pragma unroll
    for (int kt2 = 0; kt2 < 8; ++kt2) {
      const int kt = kc * 8 + kt2;
      bf16x8_t bfr[8];
      #pragma unroll
      for (int n = 0; n < 8; ++n)
        bfr[n] = *reinterpret_cast<const bf16x8_t*>(
            Wp + (size_t)((wn * 8 + n) * KT + kt) * 512 + (size_t)lane * 8);
      const bf16x8_t af = *reinterpret_cast<const bf16x8_t*>(
          lds_bf16(As, wm * 16 + fr, kt2 * 4 + fq, 0));
      #pragma unroll
      for (int n = 0; n < 8; ++n)
        acc[n] = __builtin_amdgcn_mfma_f32_16x16x32_bf16(af, bfr[n], acc[n], 0, 0, 0);
    }
  }

  #pragma unroll
  for (int n = 0; n < 8; ++n)
    #pragma unroll
    for (int j = 0; j < 4; ++j)
      R[wm * 16 + fq * 4 + j][wn * 128 + n * 16 + fr] = acc[n][j] + bld[n];
  __syncthreads();

  const int r = tid >> 3, p = tid & 7;
  const int grow = m0 + r;
  const int ar = (grow < M) ? grow : (M - 1);
  float4 vbuf[8];
  float sum = 0.f, sq = 0.f;
  #pragma unroll
  for (int i = 0; i < 8; ++i) {
    float4 v = *reinterpret_cast<const float4*>(&R[r][p * 32 + i * 4]);
    const float4 x = *reinterpret_cast<const float4*>(X + (size_t)ar * 256 + p * 32 + i * 4);
    v.x += x.x; v.y += x.y; v.z += x.z; v.w += x.w;
    vbuf[i] = v;
    sum += v.x + v.y + v.z + v.w;
    sq += v.x * v.x + v.y * v.y + v.z * v.z + v.w * v.w;
  }
  sum += __shfl_xor(sum, 1); sum += __shfl_xor(sum, 2); sum += __shfl_xor(sum, 4);
  sq  += __shfl_xor(sq, 1);  sq  += __shfl_xor(sq, 2);  sq  += __shfl_xor(sq, 4);
  const float mean = sum * (1.f / 256.f);
  const float var = sq * (1.f / 256.f) - mean * mean;
  const float sc = rsqrtf(var + LN_EPS);
  if (grow < M) {
    #pragma unroll
    for (int i = 0; i < 8; ++i) {
      const float4 gg = *reinterpret_cast<const float4*>(g + p * 32 + i * 4);
      const float4 bb = *reinterpret_cast<const float4*>(beta + p * 32 + i * 4);
      float4 o;
      o.x = (vbuf[i].x - mean) * sc * gg.x + bb.x;
      o.y = (vbuf[i].y - mean) * sc * gg.y + bb.y;
      o.z = (vbuf[i].z - mean) * sc * gg.z + bb.z;
      o.w = (vbuf[i].w - mean) * sc * gg.w + bb.w;
      *reinterpret_cast<float4*>(out + (size_t)grow * 256 + p * 32 + i * 4) = o;
    }
  }
}

// ---------------------------------------------------------------------------
// MEGA: value projection + self-attention, interleaved block mapping
// (R16-proven: 1216 attn blocks x 16 q-rows, bid%3==2 interleave).
// K stride 38, V stride 36 in LDS, u32 staging, launch_bounds(256,3).
// ---------------------------------------------------------------------------
struct AttnSh { u16 Kb[304][38]; u16 Vb[304][36]; float pbuf[4][304]; };
struct ValSh  { __bf16 As[64 * 256]; };

__global__ __launch_bounds__(256, 3) void val_attn(
    const float* __restrict__ src, const __bf16* __restrict__ Bpk,
    const float* __restrict__ b_val, bf16* __restrict__ valb,
    const float* __restrict__ qh, const float* __restrict__ kh,
    const float* __restrict__ vh, float* __restrict__ sa)
{
  __shared__ union { AttnSh a; ValSh v; } sh;
  const int tid = threadIdx.x;
  const int w = tid >> 6, lane = tid & 63;
  const int fr = lane & 15, fq = lane >> 4;

  const int bid = blockIdx.x;
  const bool is_attn = (bid < 3648) && (bid % 3 == 2);
  const int wid = is_attn ? (bid / 3)
                          : (bid < 3648 ? (bid / 3) * 2 + (bid % 3) : bid - AGRID);

  if (!is_attn) {
    // ---------------- value projection ----------------
    __bf16* As = sh.v.As;
    const __bf16* Wp = Bpk + (size_t)FR_WVAL * 512;
    const size_t m0 = (size_t)wid * 64;

    float bld[4];
    #pragma unroll
    for (int n = 0; n < 4; ++n) bld[n] = b_val[w * 64 + n * 16 + fr];

    // stage: all 16 loads in flight, then LDS writes (swizzled)
    const float* g = src + (m0 + (size_t)w * 16) * 256 + lane * 4;
    float4 p[16];
    #pragma unroll
    for (int j = 0; j < 16; ++j)
      p[j] = *reinterpret_cast<const float4*>(g + (size_t)j * 256);
    #pragma unroll
    for (int j = 0; j < 16; ++j)
      *reinterpret_cast<bf16x4_t*>(lds_bf16(As, w * 16 + j, lane >> 1, (lane & 1) * 4)) =
          bf16x4_t{ (__bf16)p[j].x, (__bf16)p[j].y, (__bf16)p[j].z, (__bf16)p[j].w };

    f32x4_t acc[4][4];
    const f32x4_t zz = {0.f, 0.f, 0.f, 0.f};
    #pragma unroll
    for (int m = 0; m < 4; ++m)
      #pragma unroll
      for (int n = 0; n < 4; ++n) acc[m][n] = zz;

    const __bf16* wpl = Wp + (size_t)lane * 8;
    __syncthreads();

    #pragma unroll
    for (int kt = 0; kt < 8; ++kt) {
      bf16x8_t bfr[4];
      #pragma unroll
      for (int n = 0; n < 4; ++n)
        bfr[n] = *reinterpret_cast<const bf16x8_t*>(wpl + (size_t)((w * 4 + n) * 8 + kt) * 512);
      bf16x8_t af[4];
      #pragma unroll
      for (int m = 0; m < 4; ++m)
        af[m] = *reinterpret_cast<const bf16x8_t*>(
            lds_bf16(As, m * 16 + fr, kt * 4 + fq, 0));
      #pragma unroll
      for (int m = 0; m < 4; ++m)
        #pragma unroll
        for (int n = 0; n < 4; ++n)
          acc[m][n] = __builtin_amdgcn_mfma_f32_16x16x32_bf16(af[m], bfr[n], acc[m][n], 0, 0, 0);
    }

    __syncthreads();
    #pragma unroll
    for (int m = 0; m < 4; ++m)
      #pragma unroll
      for (int n = 0; n < 4; ++n)
        #pragma unroll
        for (int j = 0; j < 4; ++j)
          *lds_bf16(As, m * 16 + fq * 4 + j, w * 8 + n * 2 + (fr >> 3), fr & 7) =
              (__bf16)(acc[m][n][j] + bld[n]);
    __syncthreads();
    #pragma unroll
    for (int i = 0; i < 8; ++i) {
      const int pby = i * 4096 + tid * 16;
      const int row = pby >> 9;
      const int chunk = (pby & 511) >> 4;
      const bf16x8_t v = *reinterpret_cast<const bf16x8_t*>(lds_bf16(As, row, chunk, 0));
      *reinterpret_cast<bf16x8_t*>(
          reinterpret_cast<char*>(valb + (m0 + row) * 256) + (pby & 511)) = v;
    }
    return;
  }

  // ---------------- self-attention (16 q-rows per block) ----------------
  auto& Kb = sh.a.Kb;
  auto& Vb = sh.a.Vb;
  auto& pbuf = sh.a.pbuf;
  const int qt = wid % 19;
  const int bh = wid / 19;
  const int h = bh & 7, b = bh >> 3;
  const size_t base = ((size_t)b * Qq) * Cc + h * DHh;

  for (int idx = tid; idx < 304 * 16; idx += 256) {
    const int k = idx >> 4, dd = idx & 15;
    u32 kw = 0, vw = 0;
    if (k < Qq) {
      const float2 kf = *reinterpret_cast<const float2*>(kh + base + (size_t)k * Cc + 2 * dd);
      const float2 vf = *reinterpret_cast<const float2*>(vh + base + (size_t)k * Cc + 2 * dd);
      kw = (u32)f2bf(kf.x * 0.17677669529663687f) |
           ((u32)f2bf(kf.y * 0.17677669529663687f) << 16);
      vw = (u32)f2bf(vf.x) | ((u32)f2bf(vf.y) << 16);
    }
    *reinterpret_cast<u32*>(&Kb[k][2 * dd]) = kw;
    *reinterpret_cast<u32*>(&Vb[k][2 * dd]) = vw;
  }
  __syncthreads();

  const int qtr = lane >> 4, dp = lane & 15;

  for (int r = 0; r < 4; ++r) {
    const int q0 = qt * 16 + w * 4 + r;
    const int q = (q0 < Qq) ? q0 : (Qq - 1);
    const float* qp = qh + base + (size_t)q * Cc;
    float qv[32];
    #pragma unroll
    for (int i = 0; i < 8; ++i) {
      const float4 t = reinterpret_cast<const float4*>(qp)[i];
      qv[i*4+0] = t.x; qv[i*4+1] = t.y; qv[i*4+2] = t.z; qv[i*4+3] = t.w;
    }

    float e[5];
    float mx = -1e30f;
    #pragma unroll
    for (int i = 0; i < 5; ++i) {
      const int k = lane + i * 64;
      if (k < Qq) {
        const u32* kp = reinterpret_cast<const u32*>(&Kb[k][0]);
        float s = 0.f;
        #pragma unroll
        for (int d2 = 0; d2 < 16; ++d2) {
          const u32 kw = kp[d2];
          s = fmaf(qv[2*d2], bfbits_lo(kw), s);
          s = fmaf(qv[2*d2+1], bfbits_hi(kw), s);
        }
        e[i] = s;
      } else {
        e[i] = -1e30f;
      }
      mx = fmaxf(mx, e[i]);
    }
    #pragma unroll
    for (int o = 32; o; o >>= 1) mx = fmaxf(mx, __shfl_xor(mx, o));
    float ssum = 0.f;
    #pragma unroll
    for (int i = 0; i < 5; ++i) { e[i] = __expf(e[i] - mx); ssum += e[i]; }
    #pragma unroll
    for (int o = 32; o; o >>= 1) ssum += __shfl_xor(ssum, o);
    const float inv = 1.f / ssum;
    #pragma unroll
    for (int i = 0; i < 5; ++i) {
      const int k = lane + i * 64;
      if (k < 304) pbuf[w][k] = (k < Qq) ? e[i] * inv : 0.f;
    }
    __syncthreads();

    float accA = 0.f, accB = 0.f;
    const float* prow = pbuf[w] + qtr * 76;
    #pragma unroll 4
    for (int j4 = 0; j4 < 19; ++j4) {
      const float4 pv4 = *reinterpret_cast<const float4*>(prow + j4 * 4);
      const int kb = qtr * 76 + j4 * 4;
      const u32 v0 = *reinterpret_cast<const u32*>(&Vb[kb + 0][2*dp]);
      const u32 v1 = *reinterpret_cast<const u32*>(&Vb[kb + 1][2*dp]);
      const u32 v2 = *reinterpret_cast<const u32*>(&Vb[kb + 2][2*dp]);
      const u32 v3 = *reinterpret_cast<const u32*>(&Vb[kb + 3][2*dp]);
      accA = fmaf(pv4.x, bfbits_lo(v0), accA); accB = fmaf(pv4.x, bfbits_hi(v0), accB);
      accA = fmaf(pv4.y, bfbits_lo(v1), accA); accB = fmaf(pv4.y, bfbits_hi(v1), accB);
      accA = fmaf(pv4.z, bfbits_lo(v2), accA); accB = fmaf(pv4.z, bfbits_hi(v2), accB);
      accA = fmaf(pv4.w, bfbits_lo(v3), accA); accB = fmaf(pv4.w, bfbits_hi(v3), accB);
    }
    accA += __shfl_xor(accA, 16); accA += __shfl_xor(accA, 32);
    accB += __shfl_xor(accB, 16); accB += __shfl_xor(accB, 32);
    if (q0 < Qq && lane < 16) {
      float2 st; st.x = accA; st.y = accB;
      *reinterpret_cast<float2*>(sa + base + (size_t)q * Cc + 2 * dp) = st;
    }
    __syncthreads();
  }
}

// ---------------------------------------------------------------------------
// Deformable sampling: one wave per (b,q,h). lane = pt*16 + dp.
// ---------------------------------------------------------------------------
__global__ __launch_bounds__(256) void deform_kernel(
    const float* __restrict__ offb, const float* __restrict__ awl,
    const float* __restrict__ refp, const bf16* __restrict__ value,
    float* __restrict__ accp)
{
  const int gw = (int)((blockIdx.x * (size_t)blockDim.x + threadIdx.x) >> 6);
  if (gw >= Bb * Qq * NHh) return;
  const int lane = threadIdx.x & 63;
  const int h = gw % NHh;
  const int t = gw / NHh;
  const int qi = t % Qq;
  const int b = t / Qq;
  const int pt = lane >> 4;
  const int dp = lane & 15;

  const float* awp = awl + (size_t)(b * Qq + qi) * 128 + h * 16;
  float e[16];
  {
    const float4 e0 = *reinterpret_cast<const float4*>(awp + 0);
    const float4 e1 = *reinterpret_cast<const float4*>(awp + 4);
    const float4 e2 = *reinterpret_cast<const float4*>(awp + 8);
    const float4 e3 = *reinterpret_cast<const float4*>(awp + 12);
    e[0]=e0.x; e[1]=e0.y; e[2]=e0.z; e[3]=e0.w;
    e[4]=e1.x; e[5]=e1.y; e[6]=e1.z; e[7]=e1.w;
    e[8]=e2.x; e[9]=e2.y; e[10]=e2.z; e[11]=e2.w;
    e[12]=e3.x; e[13]=e3.y; e[14]=e3.z; e[15]=e3.w;
  }
  float mx = -1e30f;
  #pragma unroll
  for (int i = 0; i < 16; ++i) mx = fmaxf(mx, e[i]);
  float s = 0.f;
  #pragma unroll
  for (int i = 0; i < 16; ++i) { e[i] = __expf(e[i] - mx); s += e[i]; }
  const float inv = 1.f / s;

  const float* offp = offb + (size_t)(b * Qq + qi) * Cc + h * 32;
  const float* rp = refp + (size_t)(b * Qq + qi) * 8;
  const int lH[4] = {128, 64, 32, 16};
  const int lW[4] = {128, 64, 32, 16};
  const int lS[4] = {0, 16384, 20480, 21504};

  const u16* vbase = reinterpret_cast<const u16*>(value) + (size_t)h * 32 + 2 * dp;

  float accx = 0.f, accy = 0.f;
  #pragma unroll
  for (int l = 0; l < 4; ++l) {
    const int Hl = lH[l], Wl = lW[l], st = lS[l];
    const float rx = rp[l * 2 + 0], ry = rp[l * 2 + 1];
    const float ax = offp[l * 8 + pt * 2 + 0];
    const float ay = offp[l * 8 + pt * 2 + 1];
    const float x = (rx + ax / (float)Wl) * (float)Wl - 0.5f;
    const float y = (ry + ay / (float)Hl) * (float)Hl - 0.5f;
    const float x0f = floorf(x), y0f = floorf(y);
    const float wx = x - x0f, wy = y - y0f;
    const int x0 = (int)x0f, y0 = (int)y0f;
    const float wp = e[l * 4 + pt] * inv;
    #pragma unroll
    for (int dy = 0; dy < 2; ++dy) {
      #pragma unroll
      for (int dx = 0; dx < 2; ++dx) {
        const int xi = x0 + dx, yi = y0 + dy;
        if (xi >= 0 && xi < Wl && yi >= 0 && yi < Hl) {
          const float wgt = wp * (dx ? wx : 1.f - wx) * (dy ? wy : 1.f - wy);
          const u32 v = *reinterpret_cast<const u32*>(
              vbase + (size_t)(b * (size_t)Ss + st + yi * Wl + xi) * Cc);
          accx = fmaf(wgt, bfbits_lo(v), accx);
          accy = fmaf(wgt, bfbits_hi(v), accy);
        }
      }
    }
  }
  accx += __shfl_xor(accx, 16); accx += __shfl_xor(accx, 32);
  accy += __shfl_xor(accy, 16); accy += __shfl_xor(accy, 32);
  if (lane < 16) {
    float2 st2; st2.x = accx; st2.y = accy;
    *reinterpret_cast<float2*>(accp + (size_t)(b * Qq + qi) * Cc + h * 32 + 2 * dp) = st2;
  }
}

// ---------------------------------------------------------------------------
extern "C" void kernel_launch(void* const* d_in, const int* in_sizes, int n_in,
                              void* d_out, int out_size, void* d_ws, size_t ws_size,
                              hipStream_t stream) {
  const float* tgt   = (const float*)d_in[0];
  const float* qpos  = (const float*)d_in[2];
  const float* refp  = (const float*)d_in[3];
  const float* src   = (const float*)d_in[4];
  const float* wq = (const float*)d_in[8];   const float* bq = (const float*)d_in[9];
  const float* wk = (const float*)d_in[10];  const float* bk = (const float*)d_in[11];
  const float* wv = (const float*)d_in[12];  const float* bv = (const float*)d_in[13];
  const float* wo = (const float*)d_in[14];  const float* bo = (const float*)d_in[15];
  const float* w_off = (const float*)d_in[16];  const float* b_off = (const float*)d_in[17];
  const float* w_attn = (const float*)d_in[18]; const float* b_attn = (const float*)d_in[19];
  const float* w_val = (const float*)d_in[20];  const float* b_val = (const float*)d_in[21];
  const float* w_out = (const float*)d_in[22];  const float* b_out = (const float*)d_in[23];
  const float* w1 = (const float*)d_in[24];  const float* b1 = (const float*)d_in[25];
  const float* w2 = (const float*)d_in[26];  const float* b2 = (const float*)d_in[27];
  const float* ln2g = (const float*)d_in[28]; const float* ln2b = (const float*)d_in[29];
  const float* ln1g = (const float*)d_in[30]; const float* ln1b = (const float*)d_in[31];
  const float* ln3g = (const float*)d_in[32]; const float* ln3b = (const float*)d_in[33];

  float* fws = (float*)d_ws;
  const size_t NBQ = (size_t)Bb * Qq * Cc;  // 614400
  float* qhb  = fws;
  float* khb  = qhb  + NBQ;
  float* vhb  = khb  + NBQ;
  float* sab  = vhb  + NBQ;
  float* tgt1 = sab  + NBQ;
  float* offb = tgt1 + NBQ;
  float* accb = offb + NBQ;
  float* t2nb = accb + NBQ;
  float* awlb = t2nb + NBQ;                       // 2400*128
  float* ffhb = awlb + (size_t)Bb * Qq * 128;     // 2400*1024
  bf16*  valb = (bf16*)(ffhb + (size_t)Bb * Qq * DFFf);   // 174080*256 bf16
  __bf16* Bpk = (__bf16*)(valb + (size_t)Bb * Ss * Cc);   // 1984*512 bf16

  const int MQ = Bb * Qq;          // 2400
  const int MT = (MQ + 63) / 64;   // 38
  const int MT2 = (MQ + 31) / 32;  // 75
  dim3 blk(256, 1, 1);

  pack_weights<<<dim3((FR_TOTAL + 3) / 4), blk, 0, stream>>>(
      wq, wk, wv, wo, w_val, w_off, w_attn, w_out, w1, w2, Bpk);

  gemm_qkv<<<dim3(6, MT), blk, 0, stream>>>(tgt, qpos, Bpk, bq, bk, bv, qhb, khb, vhb, MQ);

  // value projection (2720 blocks) interleaved with self-attention (1216)
  val_attn<<<dim3(TGRID), blk, 0, stream>>>(
      src, Bpk, b_val, valb, qhb, khb, vhb, sab);

  // wo projection + residual(tgt) + ln2 -> tgt1
  gemm_ln<8><<<dim3(MT2), blk, 0, stream>>>(
      sab, Bpk + (size_t)FR_WO * 512, bo, tgt, ln2g, ln2b, tgt1, MQ);

  gemm_offattn<<<dim3(3, MT), blk, 0, stream>>>(tgt1, qpos, Bpk, b_off, b_attn, offb, awlb, MQ);

  deform_kernel<<<dim3(Bb * Qq * NHh / 4), blk, 0, stream>>>(offb, awlb, refp, valb, accb);

  // w_out projection + residual(tgt1) + ln1 -> t2nb
  gemm_ln<8><<<dim3(MT2), blk, 0, stream>>>(
      accb, Bpk + (size_t)FR_WOUT * 512, b_out, tgt1, ln1g, ln1b, t2nb, MQ);

  // FFN
  gemm64<8, true><<<dim3(8, MT), blk, 0, stream>>>(t2nb, nullptr, Bpk + (size_t)FR_W1 * 512, b1, ffhb, MQ, DFFf);
  gemm_ln<32><<<dim3(MT2), blk, 0, stream>>>(
      ffhb, Bpk + (size_t)FR_W2 * 512, b2, t2nb, ln3g, ln3b, (float*)d_out, MQ);
}